// Round 9
// baseline (859.941 us; speedup 1.0000x reference)
//
#include <hip/hip_runtime.h>
#include <cstdint>
#include <cstddef>

#define NVARS 2048
#define DG    256
#define NSLOT 8
#define NN2   (NVARS*NVARS)
#define K_SEL 2097152u
#define CAP   (1u<<18)
#define KS    512   // packed row stride: [hi(256) | lo(256)]

typedef __attribute__((ext_vector_type(8))) short short8;
typedef __attribute__((ext_vector_type(8))) unsigned short ushort8;
typedef __attribute__((ext_vector_type(4))) float floatx4;

// ---------------- static device scratch ----------------
__device__ __align__(16) unsigned short g_ebig[NSLOT][2][NVARS*KS]; // split E (emb1/emb2)
__device__ __align__(16) unsigned short g_wbig[NSLOT][2][DG*KS];    // split W (w1/w2)
__device__ __align__(16) unsigned short g_abig[NSLOT][NVARS*KS];    // split nv1
__device__ __align__(16) unsigned short g_bbig[NSLOT][NVARS*KS];    // split nv2
__device__ unsigned g_hist[NSLOT][2048];
__device__ unsigned g_cand[NSLOT][CAP];
__device__ unsigned g_candk[NSLOT][CAP];   // cached fkey per candidate
__device__ unsigned g_state[NSLOT][16];
// state: 0 primary, 1 first_occ, 2 prefix, 3 krem, 4 tu, 7 cutoff, 8 cand_cnt
__device__ unsigned g_done[NSLOT];         // gemm_s block completion counter
__device__ unsigned g_done2[NSLOT];        // collect block completion counter
__device__ float g_scal[2];

__device__ __forceinline__ unsigned fkey(float x){
  unsigned b = __float_as_uint(x);
  return (b & 0x80000000u) ? ~b : (b | 0x80000000u);
}
__device__ __forceinline__ unsigned short f2bf(float v){
  unsigned u = __float_as_uint(v);
  return (unsigned short)((u + 0x7FFFu + ((u >> 16) & 1u)) >> 16);
}
__device__ __forceinline__ void async16(void* lds, const void* g){
  __builtin_amdgcn_global_load_lds(
      (const __attribute__((address_space(1))) unsigned int*)g,
      (__attribute__((address_space(3))) unsigned int*)lds, 16, 0, 0);
}

// ---------------- prep ----------------
__global__ __launch_bounds__(256) void k_prep(const int* __restrict__ tind,
                                              const int* __restrict__ epoch_p){
  int tid = threadIdx.x;
  if (tid < NSLOT){
    int t = tind[tid];
    int fo = tid;
    for (int b = 0; b < tid; b++){ if (tind[b] == t){ fo = b; break; } }
    g_state[tid][0] = (fo == tid) ? 1u : 0u;
    g_state[tid][1] = (unsigned)fo;
    g_state[tid][2] = 0u;
    g_state[tid][3] = K_SEL;
    g_state[tid][4] = 0u;
    g_state[tid][7] = 0x7FFFFFFFu;
    g_state[tid][8] = 0u;
    g_done[tid]  = 0u;
    g_done2[tid] = 0u;
  }
  if (tid == 0){
    double pd = (double)epoch_p[0] / 5.0;
    if (pd > 0.9) pd = 0.9;
    g_scal[0] = (float)(1.0 - pd);
    g_scal[1] = (float)pd;
  }
  unsigned* h = (unsigned*)g_hist;
  for (int i = tid; i < NSLOT*2048; i += 256) h[i] = 0u;
}

// ---------------- split E and W into [hi|lo] bf16 (streaming, BW-bound) ----
__global__ __launch_bounds__(256) void k_split(
    const float* __restrict__ emb1, const float* __restrict__ emb2,
    const float* __restrict__ w1,  const float* __restrict__ w2,
    const int* __restrict__ tind){
  int z = blockIdx.z; int s = z >> 1; int side = z & 1;
  if (!g_state[s][0]) return;
  int t = tind[s];
  int flat = blockIdx.x*256 + threadIdx.x;   // 0 .. 73727
  const float* src;
  unsigned short* dst;
  if (flat < 65536){           // E: 2048 rows x 32 granules of 8
    int row = flat >> 5, g8 = flat & 31;
    src = (side ? emb2 : emb1) + (size_t)t*NVARS*DG + (size_t)row*DG + g8*8;
    dst = g_ebig[s][side] + (size_t)row*KS + g8*8;
  } else {                     // W: 256 rows x 32 granules
    int f2 = flat - 65536;
    int row = f2 >> 5, g8 = f2 & 31;
    src = (side ? w2 : w1) + (size_t)t*DG*DG + (size_t)row*DG + g8*8;
    dst = g_wbig[s][side] + (size_t)row*KS + g8*8;
  }
  float4 v0 = *(const float4*)src;
  float4 v1 = *(const float4*)(src + 4);
  float a[8] = {v0.x,v0.y,v0.z,v0.w,v1.x,v1.y,v1.z,v1.w};
  ushort8 hi8, lo8;
  #pragma unroll
  for (int j = 0; j < 8; j++){
    unsigned short hb = f2bf(a[j]);
    float hv = __uint_as_float(((unsigned)hb) << 16);
    hi8[j] = hb;
    lo8[j] = f2bf(a[j] - hv);
  }
  *(ushort8*)dst         = hi8;
  *(ushort8*)(dst + 256) = lo8;
}

// ---------------- GEMM1 (bf16 MFMA, fused hi/lo single-pass split-K):
//   nv = tanh(E@W^T + b)
// epilogue: LDS bounce (Cs aliased over dead staging) -> tanh -> hi/lo pack
__global__ __launch_bounds__(256, 2) void k_gemm_nv(
    const float* __restrict__ b1, const float* __restrict__ b2,
    const int* __restrict__ tind){
  int z = blockIdx.z; int s = z >> 1; int side = z & 1;
  if (!g_state[s][0]) return;
  int t = tind[s];
  const unsigned short* __restrict__ A = g_ebig[s][side];
  const unsigned short* __restrict__ B = g_wbig[s][side];
  const float* __restrict__ bias = (side ? b2 : b1) + (size_t)t*DG;
  unsigned short* __restrict__ dst = side ? g_bbig[s] : g_abig[s];
  __shared__ __align__(16) unsigned short SM[2][128*128]; // As | Bs, 64 KB
  unsigned short* As = SM[0];
  unsigned short* Bs = SM[1];
  int tid = threadIdx.x;
  int lane = tid & 63, wv = tid >> 6;
  int rowBase = blockIdx.y*128, colBase = blockIdx.x*128;
  int rW = (wv >> 1)*64, cW = (wv & 1)*64;
  int m = lane & 15, q = lane >> 4;
  int rl4 = lane >> 4;   // sub-row within 4-row chunk (0..3)
  int gl  = lane & 15;   // granule within 128-short row (16B granules)
  floatx4 acc[4][4] = {};
  for (int k0 = 0; k0 < 256; k0 += 64){
    #pragma unroll
    for (int t8 = 0; t8 < 8; t8++){
      int rloc = wv*32 + t8*4 + rl4;
      int g = (gl & 8) | ((gl ^ rloc) & 7);
      int off = ((g & 8) ? 256 : 0) + k0 + (g & 7)*8;
      async16(&As[(wv*32 + t8*4)*128], A + (size_t)(rowBase + rloc)*KS + off);
      async16(&Bs[(wv*32 + t8*4)*128], B + (size_t)(colBase + rloc)*KS + off);
    }
    __syncthreads();
    #pragma unroll
    for (int kk = 0; kk < 2; kk++){
      short8 ah[4], bh[4], al[4], bl[4];
      #pragma unroll
      for (int i = 0; i < 4; i++){
        int rA = rW + i*16 + m;
        int pa = (kk*4 + q) ^ (rA & 7);
        ah[i] = *(const short8*)&As[rA*128 + pa*8];
        al[i] = *(const short8*)&As[rA*128 + (8 + pa)*8];
        int rB = cW + i*16 + m;
        int pb = (kk*4 + q) ^ (rB & 7);
        bh[i] = *(const short8*)&Bs[rB*128 + pb*8];
        bl[i] = *(const short8*)&Bs[rB*128 + (8 + pb)*8];
      }
      #pragma unroll
      for (int i = 0; i < 4; i++)
        #pragma unroll
        for (int j = 0; j < 4; j++){
          acc[i][j] = __builtin_amdgcn_mfma_f32_16x16x32_bf16(ah[i], bh[j], acc[i][j], 0, 0, 0);
          acc[i][j] = __builtin_amdgcn_mfma_f32_16x16x32_bf16(al[i], bh[j], acc[i][j], 0, 0, 0);
          acc[i][j] = __builtin_amdgcn_mfma_f32_16x16x32_bf16(ah[i], bl[j], acc[i][j], 0, 0, 0);
        }
    }
    __syncthreads();
  }
  // epilogue: two 64-col halves through Cs (aliased over dead staging)
  float (*Cs)[68] = (float(*)[68])SM;
  for (int h = 0; h < 2; h++){
    if ((wv & 1) == h){
      #pragma unroll
      for (int i = 0; i < 4; i++)
        #pragma unroll
        for (int j = 0; j < 4; j++)
          #pragma unroll
          for (int r = 0; r < 4; r++)
            Cs[rW + i*16 + q*4 + r][j*16 + m] = acc[i][j][r];
    }
    __syncthreads();
    #pragma unroll
    for (int it = 0; it < 4; it++){
      int row = it*32 + (tid >> 3);
      int c8  = (tid & 7)*8;
      float4 va = *(const float4*)&Cs[row][c8];
      float4 vb = *(const float4*)&Cs[row][c8 + 4];
      float v[8] = {va.x,va.y,va.z,va.w,vb.x,vb.y,vb.z,vb.w};
      int colb = colBase + h*64 + c8;
      ushort8 hi8, lo8;
      #pragma unroll
      for (int j = 0; j < 8; j++){
        float e = tanhf(v[j] + bias[colb + j]);
        unsigned short hb = f2bf(e);
        float hv = __uint_as_float(((unsigned)hb) << 16);
        hi8[j] = hb;
        lo8[j] = f2bf(e - hv);
      }
      unsigned short* rp = dst + (size_t)(rowBase + row)*KS;
      *(ushort8*)(rp + colb)       = hi8;
      *(ushort8*)(rp + 256 + colb) = lo8;
    }
    __syncthreads();
  }
}

// ---------------- GEMM2 (bf16 MFMA, fused hi/lo single-pass split-K):
//   a = (1-p)*init + p*(nv1@nv2^T)   [r5/r7-exact config: 512 thr, 128^2]
// Tail: last finishing block per slot (device-scope counter + fences) runs
// the pass-1 bin selection (was k_select1) with all 512 threads.
__global__ __launch_bounds__(512, 2) void k_gemm_s(const float* __restrict__ init,
                                                   float* __restrict__ out){
  int s = blockIdx.z;
  if (!g_state[s][0]) return;
  const unsigned short* __restrict__ A = g_abig[s];
  const unsigned short* __restrict__ B = g_bbig[s];
  __shared__ __align__(16) unsigned short SM[2][128*128]; // As | Bs, 64 KB total
  __shared__ unsigned hloc[2048];
  __shared__ unsigned s_last;
  unsigned short* As = SM[0];
  unsigned short* Bs = SM[1];
  int tid = threadIdx.x;
  int lane = tid & 63, wv = tid >> 6;           // 8 waves: 2 row-groups x 4 col-groups
  int rowBase = blockIdx.y*128, colBase = blockIdx.x*128;
  int rW = (wv >> 2)*64, cW = (wv & 3)*32;
  int m = lane & 15, q = lane >> 4;
  int rl4 = lane >> 4;   // sub-row within 4-row chunk (0..3)
  int gl  = lane & 15;   // granule within 128-short row (16B granules)
  for (int i = tid; i < 2048; i += 512) hloc[i] = 0u;
  floatx4 acc[4][2] = {};
  for (int k0 = 0; k0 < 256; k0 += 64){
    #pragma unroll
    for (int t8 = 0; t8 < 4; t8++){
      int rloc = wv*16 + t8*4 + rl4;
      int g = (gl & 8) | ((gl ^ rloc) & 7);
      int off = ((g & 8) ? 256 : 0) + k0 + (g & 7)*8;
      async16(&As[(wv*16 + t8*4)*128], A + (size_t)(rowBase + rloc)*KS + off);
      async16(&Bs[(wv*16 + t8*4)*128], B + (size_t)(colBase + rloc)*KS + off);
    }
    __syncthreads();
    #pragma unroll
    for (int kk = 0; kk < 2; kk++){
      short8 ah[4], al[4], bh[2], bl[2];
      #pragma unroll
      for (int i = 0; i < 4; i++){
        int rA = rW + i*16 + m;
        int pa = (kk*4 + q) ^ (rA & 7);
        ah[i] = *(const short8*)&As[rA*128 + pa*8];
        al[i] = *(const short8*)&As[rA*128 + (8 + pa)*8];
      }
      #pragma unroll
      for (int j = 0; j < 2; j++){
        int rB = cW + j*16 + m;
        int pb = (kk*4 + q) ^ (rB & 7);
        bh[j] = *(const short8*)&Bs[rB*128 + pb*8];
        bl[j] = *(const short8*)&Bs[rB*128 + (8 + pb)*8];
      }
      #pragma unroll
      for (int i = 0; i < 4; i++)
        #pragma unroll
        for (int j = 0; j < 2; j++){
          acc[i][j] = __builtin_amdgcn_mfma_f32_16x16x32_bf16(ah[i], bh[j], acc[i][j], 0, 0, 0);
          acc[i][j] = __builtin_amdgcn_mfma_f32_16x16x32_bf16(al[i], bh[j], acc[i][j], 0, 0, 0);
          acc[i][j] = __builtin_amdgcn_mfma_f32_16x16x32_bf16(ah[i], bl[j], acc[i][j], 0, 0, 0);
        }
    }
    __syncthreads();
  }
  // epilogue: LDS bounce through Cs (aliased over dead staging bufs), two 64-col halves
  float am1 = g_scal[0], am2 = g_scal[1];
  float* __restrict__ outs = out + (size_t)s*NN2;
  float (*Cs)[68] = (float(*)[68])SM;
  for (int h = 0; h < 2; h++){
    if (((wv & 3) >> 1) == h){
      #pragma unroll
      for (int i = 0; i < 4; i++)
        #pragma unroll
        for (int j = 0; j < 2; j++)
          #pragma unroll
          for (int r = 0; r < 4; r++)
            Cs[rW + i*16 + q*4 + r][(wv & 1)*32 + j*16 + m] = acc[i][j][r];
    }
    __syncthreads();
    #pragma unroll
    for (int it = 0; it < 2; it++){
      int row = it*64 + (tid >> 3);
      int c8  = (tid & 7)*8;
      float4 va = *(const float4*)&Cs[row][c8];
      float4 vb = *(const float4*)&Cs[row][c8 + 4];
      float v[8] = {va.x,va.y,va.z,va.w,vb.x,vb.y,vb.z,vb.w};
      int grow = rowBase + row;
      int col  = colBase + h*64 + c8;
      const float* ip = init + (size_t)grow*NVARS + col;
      float4 i0 = *(const float4*)ip;
      float4 i1 = *(const float4*)(ip + 4);
      float iv[8] = {i0.x,i0.y,i0.z,i0.w,i1.x,i1.y,i1.z,i1.w};
      float o[8];
      #pragma unroll
      for (int j = 0; j < 8; j++){
        float val = am1*iv[j] + am2*v[j];
        if (grow == col + j) val = -__builtin_inff();
        o[j] = val;
        atomicAdd(&hloc[fkey(val) >> 21], 1u);
      }
      float* op = outs + (size_t)grow*NVARS + col;
      *(float4*)op       = make_float4(o[0], o[1], o[2], o[3]);
      *(float4*)(op + 4) = make_float4(o[4], o[5], o[6], o[7]);
    }
    __syncthreads();
  }
  for (int i = tid; i < 2048; i += 512){
    unsigned c = hloc[i];
    if (c) atomicAdd(&g_hist[s][i], c);
  }
  // ---- fused pass-1 bin select: last finishing block of this slot ----
  __threadfence();                               // release our hist adds
  if (tid == 0){
    unsigned r = atomicAdd(&g_done[s], 1u);
    s_last = (r == gridDim.x*gridDim.y - 1) ? 1u : 0u;
  }
  __syncthreads();
  if (!s_last) return;
  __threadfence();                               // acquire all blocks' hist adds
  unsigned* h  = (unsigned*)SM;                  // alias dead staging LDS
  unsigned* sc = ((unsigned*)SM) + 2048;
  for (int i = tid; i < 2048; i += 512) h[i] = g_hist[s][i];
  __syncthreads();
  unsigned loc[4]; unsigned own = 0u;
  int base = tid*4;
  #pragma unroll
  for (int j = 0; j < 4; j++){ loc[j] = h[base+j]; own += loc[j]; }
  sc[tid] = own;
  __syncthreads();
  for (int off = 1; off < 512; off <<= 1){
    unsigned v = (tid + off < 512) ? sc[tid+off] : 0u;
    __syncthreads();
    sc[tid] += v;
    __syncthreads();
  }
  unsigned accs = sc[tid] - own;                 // strictly-higher bins
  unsigned rank = K_SEL;
  for (int j = 3; j >= 0; j--){
    unsigned c = loc[j];
    if (c && rank > accs && rank <= accs + c){
      g_state[s][2] = (unsigned)(base + j) << 21;
      g_state[s][3] = rank - accs;
    }
    accs += c;
  }
}

// ---------------- shared select helpers (256-thread) ----------------
__device__ void desc_select(unsigned* h, unsigned* sc, int nb, unsigned rank,
                            unsigned* od, unsigned* orem, unsigned* ocnt){
  int tid = threadIdx.x;
  int per = nb >> 8;
  unsigned loc[8];
  unsigned own = 0;
  int base = tid*per;
  for (int j = 0; j < per; j++){ loc[j] = h[base+j]; own += loc[j]; }
  sc[tid] = own;
  __syncthreads();
  for (int off = 1; off < 256; off <<= 1){
    unsigned v = (tid + off < 256) ? sc[tid+off] : 0u;
    __syncthreads();
    sc[tid] += v;
    __syncthreads();
  }
  unsigned acc = sc[tid] - own;  // strictly-higher threads
  for (int j = per-1; j >= 0; j--){
    unsigned c = loc[j];
    if (c && rank > acc && rank <= acc + c){ *od = (unsigned)(base+j); *orem = rank - acc; *ocnt = c; }
    acc += c;
  }
  __syncthreads();
}
__device__ void asc_select(unsigned* h, unsigned* sc, int nb, unsigned rank,
                           unsigned* od, unsigned* orem){
  int tid = threadIdx.x;
  int per = nb >> 8;
  unsigned loc[8];
  unsigned own = 0;
  int base = tid*per;
  for (int j = 0; j < per; j++){ loc[j] = h[base+j]; own += loc[j]; }
  sc[tid] = own;
  __syncthreads();
  for (int off = 1; off < 256; off <<= 1){
    unsigned v = (tid >= off) ? sc[tid-off] : 0u;
    __syncthreads();
    sc[tid] += v;
    __syncthreads();
  }
  unsigned below = sc[tid] - own;
  for (int j = 0; j < per; j++){
    unsigned c = loc[j];
    if (c && rank > below && rank <= below + c){ *od = (unsigned)(base+j); *orem = rank - below; }
    below += c;
  }
  __syncthreads();
}

// ---------------- compact candidates + fused exact threshold ---------------
// Streaming pass fills (g_cand, g_candk); the last finishing block per slot
// (device-scope counter + fences) runs the k_final logic on cached keys.
__global__ __launch_bounds__(256) void k_collect(const float* __restrict__ out){
  int s = blockIdx.z;
  if (!g_state[s][0]) return;
  int tid = threadIdx.x;
  unsigned pb = g_state[s][2] >> 21;
  const float4* p = (const float4*)(out + (size_t)s*NN2);
  int stride = gridDim.x*256;
  for (int i = blockIdx.x*256 + tid; i < NN2/4; i += stride){
    float4 v = p[i];
    float xs[4] = {v.x, v.y, v.z, v.w};
    #pragma unroll
    for (int j = 0; j < 4; j++){
      unsigned u = fkey(xs[j]);
      if ((u >> 21) == pb){
        unsigned pos = atomicAdd(&g_state[s][8], 1u);
        if (pos < CAP){ g_cand[s][pos] = (unsigned)(i*4 + j); g_candk[s][pos] = u; }
      }
    }
  }
  // ---- last-block fusion of k_final ----
  __shared__ unsigned s_last;
  __threadfence();                               // release our cand writes
  if (tid == 0){
    unsigned r = atomicAdd(&g_done2[s], 1u);
    s_last = (r == gridDim.x - 1) ? 1u : 0u;
  }
  __syncthreads();
  if (!s_last) return;
  __threadfence();                               // acquire all cand writes
  unsigned mcnt = g_state[s][8]; if (mcnt > CAP) mcnt = CAP;
  unsigned krem = g_state[s][3];
  unsigned prefix = g_state[s][2];
  __shared__ unsigned h[2048];
  __shared__ unsigned sc[256];
  __shared__ unsigned sd, srem, scnt;
  // phase 1: fkey bits 20..10
  for (int i = tid; i < 2048; i += 256) h[i] = 0u;
  if (tid == 0){ sd = 0; srem = 1; scnt = 1; }
  __syncthreads();
  for (unsigned i = tid; i < mcnt; i += 256){
    unsigned u = g_candk[s][i];
    atomicAdd(&h[(u >> 10) & 0x7FFu], 1u);
  }
  __syncthreads();
  desc_select(h, sc, 2048, krem, &sd, &srem, &scnt);
  unsigned d1 = sd, krem2 = srem;
  __syncthreads();
  // phase 2: fkey bits 9..0
  for (int i = tid; i < 2048; i += 256) h[i] = 0u;
  __syncthreads();
  for (unsigned i = tid; i < mcnt; i += 256){
    unsigned u = g_candk[s][i];
    if (((u >> 10) & 0x7FFu) == d1) atomicAdd(&h[u & 0x3FFu], 1u);
  }
  __syncthreads();
  desc_select(h, sc, 1024, krem2, &sd, &srem, &scnt);
  unsigned d0 = sd, nek = srem, cnteq = scnt;
  __syncthreads();
  unsigned tu = prefix | (d1 << 10) | d0;
  unsigned cutoff = 0x7FFFFFFFu;
  if (nek < cnteq){
    // phase 3: nek-th smallest index, high 11 bits
    for (int i = tid; i < 2048; i += 256) h[i] = 0u;
    __syncthreads();
    for (unsigned i = tid; i < mcnt; i += 256){
      if (g_candk[s][i] == tu) atomicAdd(&h[g_cand[s][i] >> 11], 1u);
    }
    __syncthreads();
    asc_select(h, sc, 2048, nek, &sd, &srem);
    unsigned dh = sd, j2 = srem;
    __syncthreads();
    // phase 4: low 11 bits
    for (int i = tid; i < 2048; i += 256) h[i] = 0u;
    __syncthreads();
    for (unsigned i = tid; i < mcnt; i += 256){
      unsigned idx = g_cand[s][i];
      if (g_candk[s][i] == tu && (idx >> 11) == dh) atomicAdd(&h[idx & 0x7FFu], 1u);
    }
    __syncthreads();
    asc_select(h, sc, 2048, j2, &sd, &srem);
    cutoff = (dh << 11) | sd;
    __syncthreads();
  }
  if (tid == 0){ g_state[s][4] = tu; g_state[s][7] = cutoff; }
}

// ---------------- mask + tanh/relu + eye + normalize + multicast to dups ----
__global__ __launch_bounds__(256) void k_masknorm(float* __restrict__ out){
  int s = blockIdx.y;
  if (!g_state[s][0]) return;
  int r = blockIdx.x;
  int tid = threadIdx.x;
  unsigned tu = g_state[s][4];
  unsigned cutoff = g_state[s][7];
  const float4* rowp = (const float4*)(out + (size_t)s*NN2 + (size_t)r*NVARS);
  unsigned baseIdx = (unsigned)(r*NVARS);
  float4 res[2];
  double lsum = 0.0;
  #pragma unroll
  for (int t = 0; t < 2; t++){
    int c4 = tid + t*256;
    float4 a4 = rowp[c4];
    float av[4] = {a4.x, a4.y, a4.z, a4.w};
    float rv[4];
    #pragma unroll
    for (int j = 0; j < 4; j++){
      int c = c4*4 + j;
      float vv;
      if (c == r) vv = 1.0f;
      else {
        unsigned u = fkey(av[j]);
        bool keep = (u > tu) || (u == tu && (baseIdx + (unsigned)c) <= cutoff);
        vv = keep ? fmaxf(tanhf(av[j]), 0.0f) : 0.0f;
      }
      rv[j] = vv;
      lsum += (double)vv;
    }
    res[t].x = rv[0]; res[t].y = rv[1]; res[t].z = rv[2]; res[t].w = rv[3];
  }
  __shared__ double red[256];
  red[tid] = lsum;
  __syncthreads();
  for (int off = 128; off > 0; off >>= 1){
    if (tid < off) red[tid] += red[tid+off];
    __syncthreads();
  }
  float inv = 1.0f / (float)red[0];
  #pragma unroll
  for (int t = 0; t < 2; t++){
    res[t].x *= inv; res[t].y *= inv; res[t].z *= inv; res[t].w *= inv;
  }
  for (int s2 = 0; s2 < NSLOT; s2++){
    if (g_state[s2][1] == (unsigned)s){
      float4* dst = (float4*)(out + (size_t)s2*NN2 + (size_t)r*NVARS);
      dst[tid]       = res[0];
      dst[tid + 256] = res[1];
    }
  }
}

// ---------------- host launcher ----------------
extern "C" void kernel_launch(void* const* d_in, const int* in_sizes, int n_in,
                              void* d_out, int out_size, void* d_ws, size_t ws_size,
                              hipStream_t stream){
  (void)in_sizes; (void)n_in; (void)d_ws; (void)ws_size; (void)out_size;
  const float* init = (const float*)d_in[0];
  const float* emb1 = (const float*)d_in[1];
  const float* emb2 = (const float*)d_in[2];
  const float* w1   = (const float*)d_in[3];
  const float* b1   = (const float*)d_in[4];
  const float* w2   = (const float*)d_in[5];
  const float* b2   = (const float*)d_in[6];
  const int* tind   = (const int*)d_in[7];
  const int* epoch  = (const int*)d_in[8];
  float* out = (float*)d_out;

  k_prep<<<1, 256, 0, stream>>>(tind, epoch);
  k_split<<<dim3(288, 1, 16), 256, 0, stream>>>(emb1, emb2, w1, w2, tind);
  k_gemm_nv<<<dim3(2, 16, 16), 256, 0, stream>>>(b1, b2, tind);
  k_gemm_s<<<dim3(16, 16, 8), 512, 0, stream>>>(init, out);
  k_collect<<<dim3(256, 1, 8), 256, 0, stream>>>(out);
  k_masknorm<<<dim3(2048, 8), 256, 0, stream>>>(out);
}

// Round 11
// 332.254 us; speedup vs baseline: 2.5882x; 2.5882x over previous
//
#include <hip/hip_runtime.h>
#include <cstdint>
#include <cstddef>

#define NVARS 2048
#define DG    256
#define NSLOT 8
#define NN2   (NVARS*NVARS)
#define K_SEL 2097152u
#define CAP   (1u<<18)
#define KS    512   // packed row stride: [hi(256) | lo(256)]

typedef __attribute__((ext_vector_type(8))) short short8;
typedef __attribute__((ext_vector_type(8))) unsigned short ushort8;
typedef __attribute__((ext_vector_type(4))) float floatx4;

// ---------------- static device scratch ----------------
__device__ __align__(16) unsigned short g_ebig[NSLOT][2][NVARS*KS]; // split E (emb1/emb2)
__device__ __align__(16) unsigned short g_wbig[NSLOT][2][DG*KS];    // split W (w1/w2)
__device__ __align__(16) unsigned short g_abig[NSLOT][NVARS*KS];    // split nv1
__device__ __align__(16) unsigned short g_bbig[NSLOT][NVARS*KS];    // split nv2
__device__ unsigned g_hist[NSLOT][2048];
__device__ unsigned g_cand[NSLOT][CAP];
__device__ unsigned g_candk[NSLOT][CAP];   // cached fkey per candidate (kills k_final gathers)
__device__ unsigned g_state[NSLOT][16];
// state: 0 primary, 1 first_occ, 2 prefix, 3 krem, 4 tu, 7 cutoff, 8 cand_cnt
__device__ float g_scal[2];

__device__ __forceinline__ unsigned fkey(float x){
  unsigned b = __float_as_uint(x);
  return (b & 0x80000000u) ? ~b : (b | 0x80000000u);
}
__device__ __forceinline__ unsigned short f2bf(float v){
  unsigned u = __float_as_uint(v);
  return (unsigned short)((u + 0x7FFFu + ((u >> 16) & 1u)) >> 16);
}
__device__ __forceinline__ void async16(void* lds, const void* g){
  __builtin_amdgcn_global_load_lds(
      (const __attribute__((address_space(1))) unsigned int*)g,
      (__attribute__((address_space(3))) unsigned int*)lds, 16, 0, 0);
}

// ---------------- prep ----------------
__global__ __launch_bounds__(256) void k_prep(const int* __restrict__ tind,
                                              const int* __restrict__ epoch_p){
  int tid = threadIdx.x;
  if (tid < NSLOT){
    int t = tind[tid];
    int fo = tid;
    for (int b = 0; b < tid; b++){ if (tind[b] == t){ fo = b; break; } }
    g_state[tid][0] = (fo == tid) ? 1u : 0u;
    g_state[tid][1] = (unsigned)fo;
    g_state[tid][2] = 0u;
    g_state[tid][3] = K_SEL;
    g_state[tid][4] = 0u;
    g_state[tid][7] = 0x7FFFFFFFu;
    g_state[tid][8] = 0u;
  }
  if (tid == 0){
    double pd = (double)epoch_p[0] / 5.0;
    if (pd > 0.9) pd = 0.9;
    g_scal[0] = (float)(1.0 - pd);
    g_scal[1] = (float)pd;
  }
  unsigned* h = (unsigned*)g_hist;
  for (int i = tid; i < NSLOT*2048; i += 256) h[i] = 0u;
}

// ---------------- split E and W into [hi|lo] bf16 (streaming, BW-bound) ----
__global__ __launch_bounds__(256) void k_split(
    const float* __restrict__ emb1, const float* __restrict__ emb2,
    const float* __restrict__ w1,  const float* __restrict__ w2,
    const int* __restrict__ tind){
  int z = blockIdx.z; int s = z >> 1; int side = z & 1;
  if (!g_state[s][0]) return;
  int t = tind[s];
  int flat = blockIdx.x*256 + threadIdx.x;   // 0 .. 73727
  const float* src;
  unsigned short* dst;
  if (flat < 65536){           // E: 2048 rows x 32 granules of 8
    int row = flat >> 5, g8 = flat & 31;
    src = (side ? emb2 : emb1) + (size_t)t*NVARS*DG + (size_t)row*DG + g8*8;
    dst = g_ebig[s][side] + (size_t)row*KS + g8*8;
  } else {                     // W: 256 rows x 32 granules
    int f2 = flat - 65536;
    int row = f2 >> 5, g8 = f2 & 31;
    src = (side ? w2 : w1) + (size_t)t*DG*DG + (size_t)row*DG + g8*8;
    dst = g_wbig[s][side] + (size_t)row*KS + g8*8;
  }
  float4 v0 = *(const float4*)src;
  float4 v1 = *(const float4*)(src + 4);
  float a[8] = {v0.x,v0.y,v0.z,v0.w,v1.x,v1.y,v1.z,v1.w};
  ushort8 hi8, lo8;
  #pragma unroll
  for (int j = 0; j < 8; j++){
    unsigned short hb = f2bf(a[j]);
    float hv = __uint_as_float(((unsigned)hb) << 16);
    hi8[j] = hb;
    lo8[j] = f2bf(a[j] - hv);
  }
  *(ushort8*)dst         = hi8;
  *(ushort8*)(dst + 256) = lo8;
}

// ---------------- GEMM1 (bf16 MFMA, fused hi/lo single-pass split-K):
//   nv = tanh(E@W^T + b)
// epilogue: LDS bounce (Cs aliased over dead staging) -> tanh -> hi/lo pack
__global__ __launch_bounds__(256, 2) void k_gemm_nv(
    const float* __restrict__ b1, const float* __restrict__ b2,
    const int* __restrict__ tind){
  int z = blockIdx.z; int s = z >> 1; int side = z & 1;
  if (!g_state[s][0]) return;
  int t = tind[s];
  const unsigned short* __restrict__ A = g_ebig[s][side];
  const unsigned short* __restrict__ B = g_wbig[s][side];
  const float* __restrict__ bias = (side ? b2 : b1) + (size_t)t*DG;
  unsigned short* __restrict__ dst = side ? g_bbig[s] : g_abig[s];
  __shared__ __align__(16) unsigned short SM[2][128*128]; // As | Bs, 64 KB
  unsigned short* As = SM[0];
  unsigned short* Bs = SM[1];
  int tid = threadIdx.x;
  int lane = tid & 63, wv = tid >> 6;
  int rowBase = blockIdx.y*128, colBase = blockIdx.x*128;
  int rW = (wv >> 1)*64, cW = (wv & 1)*64;
  int m = lane & 15, q = lane >> 4;
  int rl4 = lane >> 4;   // sub-row within 4-row chunk (0..3)
  int gl  = lane & 15;   // granule within 128-short row (16B granules)
  floatx4 acc[4][4] = {};
  for (int k0 = 0; k0 < 256; k0 += 64){
    #pragma unroll
    for (int t8 = 0; t8 < 8; t8++){
      int rloc = wv*32 + t8*4 + rl4;
      int g = (gl & 8) | ((gl ^ rloc) & 7);
      int off = ((g & 8) ? 256 : 0) + k0 + (g & 7)*8;
      async16(&As[(wv*32 + t8*4)*128], A + (size_t)(rowBase + rloc)*KS + off);
      async16(&Bs[(wv*32 + t8*4)*128], B + (size_t)(colBase + rloc)*KS + off);
    }
    __syncthreads();
    #pragma unroll
    for (int kk = 0; kk < 2; kk++){
      short8 ah[4], bh[4], al[4], bl[4];
      #pragma unroll
      for (int i = 0; i < 4; i++){
        int rA = rW + i*16 + m;
        int pa = (kk*4 + q) ^ (rA & 7);
        ah[i] = *(const short8*)&As[rA*128 + pa*8];
        al[i] = *(const short8*)&As[rA*128 + (8 + pa)*8];
        int rB = cW + i*16 + m;
        int pb = (kk*4 + q) ^ (rB & 7);
        bh[i] = *(const short8*)&Bs[rB*128 + pb*8];
        bl[i] = *(const short8*)&Bs[rB*128 + (8 + pb)*8];
      }
      #pragma unroll
      for (int i = 0; i < 4; i++)
        #pragma unroll
        for (int j = 0; j < 4; j++){
          acc[i][j] = __builtin_amdgcn_mfma_f32_16x16x32_bf16(ah[i], bh[j], acc[i][j], 0, 0, 0);
          acc[i][j] = __builtin_amdgcn_mfma_f32_16x16x32_bf16(al[i], bh[j], acc[i][j], 0, 0, 0);
          acc[i][j] = __builtin_amdgcn_mfma_f32_16x16x32_bf16(ah[i], bl[j], acc[i][j], 0, 0, 0);
        }
    }
    __syncthreads();
  }
  // epilogue: two 64-col halves through Cs (aliased over dead staging)
  float (*Cs)[68] = (float(*)[68])SM;
  for (int h = 0; h < 2; h++){
    if ((wv & 1) == h){
      #pragma unroll
      for (int i = 0; i < 4; i++)
        #pragma unroll
        for (int j = 0; j < 4; j++)
          #pragma unroll
          for (int r = 0; r < 4; r++)
            Cs[rW + i*16 + q*4 + r][j*16 + m] = acc[i][j][r];
    }
    __syncthreads();
    #pragma unroll
    for (int it = 0; it < 4; it++){
      int row = it*32 + (tid >> 3);
      int c8  = (tid & 7)*8;
      float4 va = *(const float4*)&Cs[row][c8];
      float4 vb = *(const float4*)&Cs[row][c8 + 4];
      float v[8] = {va.x,va.y,va.z,va.w,vb.x,vb.y,vb.z,vb.w};
      int colb = colBase + h*64 + c8;
      ushort8 hi8, lo8;
      #pragma unroll
      for (int j = 0; j < 8; j++){
        float e = tanhf(v[j] + bias[colb + j]);
        unsigned short hb = f2bf(e);
        float hv = __uint_as_float(((unsigned)hb) << 16);
        hi8[j] = hb;
        lo8[j] = f2bf(e - hv);
      }
      unsigned short* rp = dst + (size_t)(rowBase + row)*KS;
      *(ushort8*)(rp + colb)       = hi8;
      *(ushort8*)(rp + 256 + colb) = lo8;
    }
    __syncthreads();
  }
}

// ---------------- GEMM2 (bf16 MFMA, fused hi/lo single-pass split-K):
//   a = (1-p)*init + p*(nv1@nv2^T)
// Best-measured config (335.4 us total): 512 thr, 128^2 tile, no prefetch,
// no swizzle, no fused tail. DO NOT graft extra code into this kernel --
// r9 showed tail fusion makes the register allocator spill the hot loop.
__global__ __launch_bounds__(512, 2) void k_gemm_s(const float* __restrict__ init,
                                                   float* __restrict__ out){
  int s = blockIdx.z;
  if (!g_state[s][0]) return;
  const unsigned short* __restrict__ A = g_abig[s];
  const unsigned short* __restrict__ B = g_bbig[s];
  __shared__ __align__(16) unsigned short SM[2][128*128]; // As | Bs, 64 KB total
  __shared__ unsigned hloc[2048];
  unsigned short* As = SM[0];
  unsigned short* Bs = SM[1];
  int tid = threadIdx.x;
  int lane = tid & 63, wv = tid >> 6;           // 8 waves: 2 row-groups x 4 col-groups
  int rowBase = blockIdx.y*128, colBase = blockIdx.x*128;
  int rW = (wv >> 2)*64, cW = (wv & 3)*32;
  int m = lane & 15, q = lane >> 4;
  int rl4 = lane >> 4;   // sub-row within 4-row chunk (0..3)
  int gl  = lane & 15;   // granule within 128-short row (16B granules)
  for (int i = tid; i < 2048; i += 512) hloc[i] = 0u;
  floatx4 acc[4][2] = {};
  for (int k0 = 0; k0 < 256; k0 += 64){
    #pragma unroll
    for (int t8 = 0; t8 < 4; t8++){
      int rloc = wv*16 + t8*4 + rl4;
      int g = (gl & 8) | ((gl ^ rloc) & 7);
      int off = ((g & 8) ? 256 : 0) + k0 + (g & 7)*8;
      async16(&As[(wv*16 + t8*4)*128], A + (size_t)(rowBase + rloc)*KS + off);
      async16(&Bs[(wv*16 + t8*4)*128], B + (size_t)(colBase + rloc)*KS + off);
    }
    __syncthreads();
    #pragma unroll
    for (int kk = 0; kk < 2; kk++){
      short8 ah[4], al[4], bh[2], bl[2];
      #pragma unroll
      for (int i = 0; i < 4; i++){
        int rA = rW + i*16 + m;
        int pa = (kk*4 + q) ^ (rA & 7);
        ah[i] = *(const short8*)&As[rA*128 + pa*8];
        al[i] = *(const short8*)&As[rA*128 + (8 + pa)*8];
      }
      #pragma unroll
      for (int j = 0; j < 2; j++){
        int rB = cW + j*16 + m;
        int pb = (kk*4 + q) ^ (rB & 7);
        bh[j] = *(const short8*)&Bs[rB*128 + pb*8];
        bl[j] = *(const short8*)&Bs[rB*128 + (8 + pb)*8];
      }
      #pragma unroll
      for (int i = 0; i < 4; i++)
        #pragma unroll
        for (int j = 0; j < 2; j++){
          acc[i][j] = __builtin_amdgcn_mfma_f32_16x16x32_bf16(ah[i], bh[j], acc[i][j], 0, 0, 0);
          acc[i][j] = __builtin_amdgcn_mfma_f32_16x16x32_bf16(al[i], bh[j], acc[i][j], 0, 0, 0);
          acc[i][j] = __builtin_amdgcn_mfma_f32_16x16x32_bf16(ah[i], bl[j], acc[i][j], 0, 0, 0);
        }
    }
    __syncthreads();
  }
  // epilogue: LDS bounce through Cs (aliased over dead staging bufs), two 64-col halves
  float am1 = g_scal[0], am2 = g_scal[1];
  float* __restrict__ outs = out + (size_t)s*NN2;
  float (*Cs)[68] = (float(*)[68])SM;
  for (int h = 0; h < 2; h++){
    if (((wv & 3) >> 1) == h){
      #pragma unroll
      for (int i = 0; i < 4; i++)
        #pragma unroll
        for (int j = 0; j < 2; j++)
          #pragma unroll
          for (int r = 0; r < 4; r++)
            Cs[rW + i*16 + q*4 + r][(wv & 1)*32 + j*16 + m] = acc[i][j][r];
    }
    __syncthreads();
    #pragma unroll
    for (int it = 0; it < 2; it++){
      int row = it*64 + (tid >> 3);
      int c8  = (tid & 7)*8;
      float4 va = *(const float4*)&Cs[row][c8];
      float4 vb = *(const float4*)&Cs[row][c8 + 4];
      float v[8] = {va.x,va.y,va.z,va.w,vb.x,vb.y,vb.z,vb.w};
      int grow = rowBase + row;
      int col  = colBase + h*64 + c8;
      const float* ip = init + (size_t)grow*NVARS + col;
      float4 i0 = *(const float4*)ip;
      float4 i1 = *(const float4*)(ip + 4);
      float iv[8] = {i0.x,i0.y,i0.z,i0.w,i1.x,i1.y,i1.z,i1.w};
      float o[8];
      #pragma unroll
      for (int j = 0; j < 8; j++){
        float val = am1*iv[j] + am2*v[j];
        if (grow == col + j) val = -__builtin_inff();
        o[j] = val;
        atomicAdd(&hloc[fkey(val) >> 21], 1u);
      }
      float* op = outs + (size_t)grow*NVARS + col;
      *(float4*)op       = make_float4(o[0], o[1], o[2], o[3]);
      *(float4*)(op + 4) = make_float4(o[4], o[5], o[6], o[7]);
    }
    __syncthreads();
  }
  for (int i = tid; i < 2048; i += 512){
    unsigned c = hloc[i];
    if (c) atomicAdd(&g_hist[s][i], c);
  }
}

// ---------------- shared select helpers ----------------
__device__ void desc_select(unsigned* h, unsigned* sc, int nb, unsigned rank,
                            unsigned* od, unsigned* orem, unsigned* ocnt){
  int tid = threadIdx.x;
  int per = nb >> 8;
  unsigned loc[8];
  unsigned own = 0;
  int base = tid*per;
  for (int j = 0; j < per; j++){ loc[j] = h[base+j]; own += loc[j]; }
  sc[tid] = own;
  __syncthreads();
  for (int off = 1; off < 256; off <<= 1){
    unsigned v = (tid + off < 256) ? sc[tid+off] : 0u;
    __syncthreads();
    sc[tid] += v;
    __syncthreads();
  }
  unsigned acc = sc[tid] - own;  // strictly-higher threads
  for (int j = per-1; j >= 0; j--){
    unsigned c = loc[j];
    if (c && rank > acc && rank <= acc + c){ *od = (unsigned)(base+j); *orem = rank - acc; *ocnt = c; }
    acc += c;
  }
  __syncthreads();
}
__device__ void asc_select(unsigned* h, unsigned* sc, int nb, unsigned rank,
                           unsigned* od, unsigned* orem){
  int tid = threadIdx.x;
  int per = nb >> 8;
  unsigned loc[8];
  unsigned own = 0;
  int base = tid*per;
  for (int j = 0; j < per; j++){ loc[j] = h[base+j]; own += loc[j]; }
  sc[tid] = own;
  __syncthreads();
  for (int off = 1; off < 256; off <<= 1){
    unsigned v = (tid >= off) ? sc[tid-off] : 0u;
    __syncthreads();
    sc[tid] += v;
    __syncthreads();
  }
  unsigned below = sc[tid] - own;
  for (int j = 0; j < per; j++){
    unsigned c = loc[j];
    if (c && rank > below && rank <= below + c){ *od = (unsigned)(base+j); *orem = rank - below; }
    below += c;
  }
  __syncthreads();
}

// ---------------- compact candidate (idx, fkey) in selected bin ------------
// Each block redundantly recomputes the pass-1 bin selection from g_hist
// (8 KB L2-hit + scan, ~1 us, fully parallel) -- removes the separate
// k_select1 launch + pipeline drain. Block 0 publishes prefix/krem.
__global__ __launch_bounds__(256) void k_collect(const float* __restrict__ out){
  int s = blockIdx.z;
  if (!g_state[s][0]) return;
  int tid = threadIdx.x;
  __shared__ unsigned h[2048];
  __shared__ unsigned sc[256];
  __shared__ unsigned sd, srem, scnt;
  for (int i = tid; i < 2048; i += 256) h[i] = g_hist[s][i];
  if (tid == 0){ sd = 0; srem = 1; scnt = 1; }
  __syncthreads();
  desc_select(h, sc, 2048, K_SEL, &sd, &srem, &scnt);
  unsigned pb = sd;
  if (blockIdx.x == 0 && tid == 0){ g_state[s][2] = sd << 21; g_state[s][3] = srem; }
  const float4* p = (const float4*)(out + (size_t)s*NN2);
  int stride = gridDim.x*256;
  for (int i = blockIdx.x*256 + tid; i < NN2/4; i += stride){
    float4 v = p[i];
    float xs[4] = {v.x, v.y, v.z, v.w};
    #pragma unroll
    for (int j = 0; j < 4; j++){
      unsigned u = fkey(xs[j]);
      if ((u >> 21) == pb){
        unsigned pos = atomicAdd(&g_state[s][8], 1u);
        if (pos < CAP){ g_cand[s][pos] = (unsigned)(i*4 + j); g_candk[s][pos] = u; }
      }
    }
  }
}

// ---------------- exact threshold + index tie-break among candidates --------
// All passes stream cached keys (g_candk) -- no scattered gathers of out.
__global__ __launch_bounds__(256) void k_final(const float* __restrict__ out){
  int s = blockIdx.x;
  if (!g_state[s][0]) return;
  int tid = threadIdx.x;
  unsigned mcnt = g_state[s][8]; if (mcnt > CAP) mcnt = CAP;
  unsigned krem = g_state[s][3];
  unsigned prefix = g_state[s][2];
  (void)out;
  __shared__ unsigned h[2048];
  __shared__ unsigned sc[256];
  __shared__ unsigned sd, srem, scnt;
  // phase 1: fkey bits 20..10
  for (int i = tid; i < 2048; i += 256) h[i] = 0u;
  if (tid == 0){ sd = 0; srem = 1; scnt = 1; }
  __syncthreads();
  for (unsigned i = tid; i < mcnt; i += 256){
    unsigned u = g_candk[s][i];
    atomicAdd(&h[(u >> 10) & 0x7FFu], 1u);
  }
  __syncthreads();
  desc_select(h, sc, 2048, krem, &sd, &srem, &scnt);
  unsigned d1 = sd, krem2 = srem;
  __syncthreads();
  // phase 2: fkey bits 9..0
  for (int i = tid; i < 2048; i += 256) h[i] = 0u;
  __syncthreads();
  for (unsigned i = tid; i < mcnt; i += 256){
    unsigned u = g_candk[s][i];
    if (((u >> 10) & 0x7FFu) == d1) atomicAdd(&h[u & 0x3FFu], 1u);
  }
  __syncthreads();
  desc_select(h, sc, 1024, krem2, &sd, &srem, &scnt);
  unsigned d0 = sd, nek = srem, cnteq = scnt;
  __syncthreads();
  unsigned tu = prefix | (d1 << 10) | d0;
  unsigned cutoff = 0x7FFFFFFFu;
  if (nek < cnteq){
    // phase 3: nek-th smallest index, high 11 bits
    for (int i = tid; i < 2048; i += 256) h[i] = 0u;
    __syncthreads();
    for (unsigned i = tid; i < mcnt; i += 256){
      if (g_candk[s][i] == tu) atomicAdd(&h[g_cand[s][i] >> 11], 1u);
    }
    __syncthreads();
    asc_select(h, sc, 2048, nek, &sd, &srem);
    unsigned dh = sd, j2 = srem;
    __syncthreads();
    // phase 4: low 11 bits
    for (int i = tid; i < 2048; i += 256) h[i] = 0u;
    __syncthreads();
    for (unsigned i = tid; i < mcnt; i += 256){
      unsigned idx = g_cand[s][i];
      if (g_candk[s][i] == tu && (idx >> 11) == dh) atomicAdd(&h[idx & 0x7FFu], 1u);
    }
    __syncthreads();
    asc_select(h, sc, 2048, j2, &sd, &srem);
    cutoff = (dh << 11) | sd;
    __syncthreads();
  }
  if (tid == 0){ g_state[s][4] = tu; g_state[s][7] = cutoff; }
}

// ---------------- mask + tanh/relu + eye + normalize + multicast to dups ----
__global__ __launch_bounds__(256) void k_masknorm(float* __restrict__ out){
  int s = blockIdx.y;
  if (!g_state[s][0]) return;
  int r = blockIdx.x;
  int tid = threadIdx.x;
  unsigned tu = g_state[s][4];
  unsigned cutoff = g_state[s][7];
  const float4* rowp = (const float4*)(out + (size_t)s*NN2 + (size_t)r*NVARS);
  unsigned baseIdx = (unsigned)(r*NVARS);
  float4 res[2];
  double lsum = 0.0;
  #pragma unroll
  for (int t = 0; t < 2; t++){
    int c4 = tid + t*256;
    float4 a4 = rowp[c4];
    float av[4] = {a4.x, a4.y, a4.z, a4.w};
    float rv[4];
    #pragma unroll
    for (int j = 0; j < 4; j++){
      int c = c4*4 + j;
      float vv;
      if (c == r) vv = 1.0f;
      else {
        unsigned u = fkey(av[j]);
        bool keep = (u > tu) || (u == tu && (baseIdx + (unsigned)c) <= cutoff);
        vv = keep ? fmaxf(tanhf(av[j]), 0.0f) : 0.0f;
      }
      rv[j] = vv;
      lsum += (double)vv;
    }
    res[t].x = rv[0]; res[t].y = rv[1]; res[t].z = rv[2]; res[t].w = rv[3];
  }
  __shared__ double red[256];
  red[tid] = lsum;
  __syncthreads();
  for (int off = 128; off > 0; off >>= 1){
    if (tid < off) red[tid] += red[tid+off];
    __syncthreads();
  }
  float inv = 1.0f / (float)red[0];
  #pragma unroll
  for (int t = 0; t < 2; t++){
    res[t].x *= inv; res[t].y *= inv; res[t].z *= inv; res[t].w *= inv;
  }
  for (int s2 = 0; s2 < NSLOT; s2++){
    if (g_state[s2][1] == (unsigned)s){
      float4* dst = (float4*)(out + (size_t)s2*NN2 + (size_t)r*NVARS);
      dst[tid]       = res[0];
      dst[tid + 256] = res[1];
    }
  }
}

// ---------------- host launcher ----------------
extern "C" void kernel_launch(void* const* d_in, const int* in_sizes, int n_in,
                              void* d_out, int out_size, void* d_ws, size_t ws_size,
                              hipStream_t stream){
  (void)in_sizes; (void)n_in; (void)d_ws; (void)ws_size; (void)out_size;
  const float* init = (const float*)d_in[0];
  const float* emb1 = (const float*)d_in[1];
  const float* emb2 = (const float*)d_in[2];
  const float* w1   = (const float*)d_in[3];
  const float* b1   = (const float*)d_in[4];
  const float* w2   = (const float*)d_in[5];
  const float* b2   = (const float*)d_in[6];
  const int* tind   = (const int*)d_in[7];
  const int* epoch  = (const int*)d_in[8];
  float* out = (float*)d_out;

  k_prep<<<1, 256, 0, stream>>>(tind, epoch);
  k_split<<<dim3(288, 1, 16), 256, 0, stream>>>(emb1, emb2, w1, w2, tind);
  k_gemm_nv<<<dim3(2, 16, 16), 256, 0, stream>>>(b1, b2, tind);
  k_gemm_s<<<dim3(16, 16, 8), 512, 0, stream>>>(init, out);
  k_collect<<<dim3(256, 1, 8), 256, 0, stream>>>(out);
  k_final<<<8, 256, 0, stream>>>(out);
  k_masknorm<<<dim3(2048, 8), 256, 0, stream>>>(out);
}

// Round 12
// 331.379 us; speedup vs baseline: 2.5950x; 1.0026x over previous
//
#include <hip/hip_runtime.h>
#include <cstdint>
#include <cstddef>

#define NVARS 2048
#define DG    256
#define NSLOT 8
#define NN2   (NVARS*NVARS)
#define K_SEL 2097152u
#define CAP   (1u<<18)
#define KS    512   // packed row stride: [hi(256) | lo(256)]

typedef __attribute__((ext_vector_type(8))) short short8;
typedef __attribute__((ext_vector_type(8))) unsigned short ushort8;
typedef __attribute__((ext_vector_type(4))) float floatx4;

// ---------------- static device scratch ----------------
__device__ __align__(16) unsigned short g_ebig[NSLOT][2][NVARS*KS]; // split E (emb1/emb2)
__device__ __align__(16) unsigned short g_wbig[NSLOT][2][DG*KS];    // split W (w1/w2)
__device__ __align__(16) unsigned short g_abig[NSLOT][NVARS*KS];    // split nv1
__device__ __align__(16) unsigned short g_bbig[NSLOT][NVARS*KS];    // split nv2
__device__ unsigned g_hist[NSLOT][2048];
__device__ unsigned g_cand[NSLOT][CAP];
__device__ unsigned g_candk[NSLOT][CAP];   // cached fkey per candidate (kills k_final gathers)
__device__ unsigned g_state[NSLOT][16];
// state: 0 primary, 1 first_occ, 2 prefix, 3 krem, 4 tu, 7 cutoff, 8 cand_cnt
__device__ float g_scal[2];

__device__ __forceinline__ unsigned fkey(float x){
  unsigned b = __float_as_uint(x);
  return (b & 0x80000000u) ? ~b : (b | 0x80000000u);
}
__device__ __forceinline__ unsigned short f2bf(float v){
  unsigned u = __float_as_uint(v);
  return (unsigned short)((u + 0x7FFFu + ((u >> 16) & 1u)) >> 16);
}
__device__ __forceinline__ void async16(void* lds, const void* g){
  __builtin_amdgcn_global_load_lds(
      (const __attribute__((address_space(1))) unsigned int*)g,
      (__attribute__((address_space(3))) unsigned int*)lds, 16, 0, 0);
}

// ---------------- prep ----------------
__global__ __launch_bounds__(256) void k_prep(const int* __restrict__ tind,
                                              const int* __restrict__ epoch_p){
  int tid = threadIdx.x;
  if (tid < NSLOT){
    int t = tind[tid];
    int fo = tid;
    for (int b = 0; b < tid; b++){ if (tind[b] == t){ fo = b; break; } }
    g_state[tid][0] = (fo == tid) ? 1u : 0u;
    g_state[tid][1] = (unsigned)fo;
    g_state[tid][2] = 0u;
    g_state[tid][3] = K_SEL;
    g_state[tid][4] = 0u;
    g_state[tid][7] = 0x7FFFFFFFu;
    g_state[tid][8] = 0u;
  }
  if (tid == 0){
    double pd = (double)epoch_p[0] / 5.0;
    if (pd > 0.9) pd = 0.9;
    g_scal[0] = (float)(1.0 - pd);
    g_scal[1] = (float)pd;
  }
  unsigned* h = (unsigned*)g_hist;
  for (int i = tid; i < NSLOT*2048; i += 256) h[i] = 0u;
}

// ---------------- split E and W into [hi|lo] bf16 (streaming, BW-bound) ----
__global__ __launch_bounds__(256) void k_split(
    const float* __restrict__ emb1, const float* __restrict__ emb2,
    const float* __restrict__ w1,  const float* __restrict__ w2,
    const int* __restrict__ tind){
  int z = blockIdx.z; int s = z >> 1; int side = z & 1;
  if (!g_state[s][0]) return;
  int t = tind[s];
  int flat = blockIdx.x*256 + threadIdx.x;   // 0 .. 73727
  const float* src;
  unsigned short* dst;
  if (flat < 65536){           // E: 2048 rows x 32 granules of 8
    int row = flat >> 5, g8 = flat & 31;
    src = (side ? emb2 : emb1) + (size_t)t*NVARS*DG + (size_t)row*DG + g8*8;
    dst = g_ebig[s][side] + (size_t)row*KS + g8*8;
  } else {                     // W: 256 rows x 32 granules
    int f2 = flat - 65536;
    int row = f2 >> 5, g8 = f2 & 31;
    src = (side ? w2 : w1) + (size_t)t*DG*DG + (size_t)row*DG + g8*8;
    dst = g_wbig[s][side] + (size_t)row*KS + g8*8;
  }
  float4 v0 = *(const float4*)src;
  float4 v1 = *(const float4*)(src + 4);
  float a[8] = {v0.x,v0.y,v0.z,v0.w,v1.x,v1.y,v1.z,v1.w};
  ushort8 hi8, lo8;
  #pragma unroll
  for (int j = 0; j < 8; j++){
    unsigned short hb = f2bf(a[j]);
    float hv = __uint_as_float(((unsigned)hb) << 16);
    hi8[j] = hb;
    lo8[j] = f2bf(a[j] - hv);
  }
  *(ushort8*)dst         = hi8;
  *(ushort8*)(dst + 256) = lo8;
}

// ---------------- GEMM1 (bf16 MFMA, fused hi/lo single-pass split-K):
//   nv = tanh(E@W^T + b)
// epilogue: LDS bounce (Cs aliased over dead staging) -> tanh -> hi/lo pack
__global__ __launch_bounds__(256, 2) void k_gemm_nv(
    const float* __restrict__ b1, const float* __restrict__ b2,
    const int* __restrict__ tind){
  int z = blockIdx.z; int s = z >> 1; int side = z & 1;
  if (!g_state[s][0]) return;
  int t = tind[s];
  const unsigned short* __restrict__ A = g_ebig[s][side];
  const unsigned short* __restrict__ B = g_wbig[s][side];
  const float* __restrict__ bias = (side ? b2 : b1) + (size_t)t*DG;
  unsigned short* __restrict__ dst = side ? g_bbig[s] : g_abig[s];
  __shared__ __align__(16) unsigned short SM[2][128*128]; // As | Bs, 64 KB
  unsigned short* As = SM[0];
  unsigned short* Bs = SM[1];
  int tid = threadIdx.x;
  int lane = tid & 63, wv = tid >> 6;
  int rowBase = blockIdx.y*128, colBase = blockIdx.x*128;
  int rW = (wv >> 1)*64, cW = (wv & 1)*64;
  int m = lane & 15, q = lane >> 4;
  int rl4 = lane >> 4;   // sub-row within 4-row chunk (0..3)
  int gl  = lane & 15;   // granule within 128-short row (16B granules)
  floatx4 acc[4][4] = {};
  for (int k0 = 0; k0 < 256; k0 += 64){
    #pragma unroll
    for (int t8 = 0; t8 < 8; t8++){
      int rloc = wv*32 + t8*4 + rl4;
      int g = (gl & 8) | ((gl ^ rloc) & 7);
      int off = ((g & 8) ? 256 : 0) + k0 + (g & 7)*8;
      async16(&As[(wv*32 + t8*4)*128], A + (size_t)(rowBase + rloc)*KS + off);
      async16(&Bs[(wv*32 + t8*4)*128], B + (size_t)(colBase + rloc)*KS + off);
    }
    __syncthreads();
    #pragma unroll
    for (int kk = 0; kk < 2; kk++){
      short8 ah[4], bh[4], al[4], bl[4];
      #pragma unroll
      for (int i = 0; i < 4; i++){
        int rA = rW + i*16 + m;
        int pa = (kk*4 + q) ^ (rA & 7);
        ah[i] = *(const short8*)&As[rA*128 + pa*8];
        al[i] = *(const short8*)&As[rA*128 + (8 + pa)*8];
        int rB = cW + i*16 + m;
        int pb = (kk*4 + q) ^ (rB & 7);
        bh[i] = *(const short8*)&Bs[rB*128 + pb*8];
        bl[i] = *(const short8*)&Bs[rB*128 + (8 + pb)*8];
      }
      #pragma unroll
      for (int i = 0; i < 4; i++)
        #pragma unroll
        for (int j = 0; j < 4; j++){
          acc[i][j] = __builtin_amdgcn_mfma_f32_16x16x32_bf16(ah[i], bh[j], acc[i][j], 0, 0, 0);
          acc[i][j] = __builtin_amdgcn_mfma_f32_16x16x32_bf16(al[i], bh[j], acc[i][j], 0, 0, 0);
          acc[i][j] = __builtin_amdgcn_mfma_f32_16x16x32_bf16(ah[i], bl[j], acc[i][j], 0, 0, 0);
        }
    }
    __syncthreads();
  }
  // epilogue: two 64-col halves through Cs (aliased over dead staging)
  float (*Cs)[68] = (float(*)[68])SM;
  for (int h = 0; h < 2; h++){
    if ((wv & 1) == h){
      #pragma unroll
      for (int i = 0; i < 4; i++)
        #pragma unroll
        for (int j = 0; j < 4; j++)
          #pragma unroll
          for (int r = 0; r < 4; r++)
            Cs[rW + i*16 + q*4 + r][j*16 + m] = acc[i][j][r];
    }
    __syncthreads();
    #pragma unroll
    for (int it = 0; it < 4; it++){
      int row = it*32 + (tid >> 3);
      int c8  = (tid & 7)*8;
      float4 va = *(const float4*)&Cs[row][c8];
      float4 vb = *(const float4*)&Cs[row][c8 + 4];
      float v[8] = {va.x,va.y,va.z,va.w,vb.x,vb.y,vb.z,vb.w};
      int colb = colBase + h*64 + c8;
      ushort8 hi8, lo8;
      #pragma unroll
      for (int j = 0; j < 8; j++){
        float e = tanhf(v[j] + bias[colb + j]);
        unsigned short hb = f2bf(e);
        float hv = __uint_as_float(((unsigned)hb) << 16);
        hi8[j] = hb;
        lo8[j] = f2bf(e - hv);
      }
      unsigned short* rp = dst + (size_t)(rowBase + row)*KS;
      *(ushort8*)(rp + colb)       = hi8;
      *(ushort8*)(rp + 256 + colb) = lo8;
    }
    __syncthreads();
  }
}

// ---------------- GEMM2 (bf16 MFMA, fused hi/lo single-pass split-K):
//   a = (1-p)*init + p*(nv1@nv2^T)
// Best-measured config (335.4/332.3 us total): 512 thr, 128^2 tile, no
// prefetch, no swizzle, no fused tail. DO NOT graft extra code into this
// kernel -- r9 showed tail fusion makes the register allocator spill.
__global__ __launch_bounds__(512, 2) void k_gemm_s(const float* __restrict__ init,
                                                   float* __restrict__ out){
  int s = blockIdx.z;
  if (!g_state[s][0]) return;
  const unsigned short* __restrict__ A = g_abig[s];
  const unsigned short* __restrict__ B = g_bbig[s];
  __shared__ __align__(16) unsigned short SM[2][128*128]; // As | Bs, 64 KB total
  __shared__ unsigned hloc[2048];
  unsigned short* As = SM[0];
  unsigned short* Bs = SM[1];
  int tid = threadIdx.x;
  int lane = tid & 63, wv = tid >> 6;           // 8 waves: 2 row-groups x 4 col-groups
  int rowBase = blockIdx.y*128, colBase = blockIdx.x*128;
  int rW = (wv >> 2)*64, cW = (wv & 3)*32;
  int m = lane & 15, q = lane >> 4;
  int rl4 = lane >> 4;   // sub-row within 4-row chunk (0..3)
  int gl  = lane & 15;   // granule within 128-short row (16B granules)
  for (int i = tid; i < 2048; i += 512) hloc[i] = 0u;
  floatx4 acc[4][2] = {};
  for (int k0 = 0; k0 < 256; k0 += 64){
    #pragma unroll
    for (int t8 = 0; t8 < 4; t8++){
      int rloc = wv*16 + t8*4 + rl4;
      int g = (gl & 8) | ((gl ^ rloc) & 7);
      int off = ((g & 8) ? 256 : 0) + k0 + (g & 7)*8;
      async16(&As[(wv*16 + t8*4)*128], A + (size_t)(rowBase + rloc)*KS + off);
      async16(&Bs[(wv*16 + t8*4)*128], B + (size_t)(colBase + rloc)*KS + off);
    }
    __syncthreads();
    #pragma unroll
    for (int kk = 0; kk < 2; kk++){
      short8 ah[4], al[4], bh[2], bl[2];
      #pragma unroll
      for (int i = 0; i < 4; i++){
        int rA = rW + i*16 + m;
        int pa = (kk*4 + q) ^ (rA & 7);
        ah[i] = *(const short8*)&As[rA*128 + pa*8];
        al[i] = *(const short8*)&As[rA*128 + (8 + pa)*8];
      }
      #pragma unroll
      for (int j = 0; j < 2; j++){
        int rB = cW + j*16 + m;
        int pb = (kk*4 + q) ^ (rB & 7);
        bh[j] = *(const short8*)&Bs[rB*128 + pb*8];
        bl[j] = *(const short8*)&Bs[rB*128 + (8 + pb)*8];
      }
      #pragma unroll
      for (int i = 0; i < 4; i++)
        #pragma unroll
        for (int j = 0; j < 2; j++){
          acc[i][j] = __builtin_amdgcn_mfma_f32_16x16x32_bf16(ah[i], bh[j], acc[i][j], 0, 0, 0);
          acc[i][j] = __builtin_amdgcn_mfma_f32_16x16x32_bf16(al[i], bh[j], acc[i][j], 0, 0, 0);
          acc[i][j] = __builtin_amdgcn_mfma_f32_16x16x32_bf16(ah[i], bl[j], acc[i][j], 0, 0, 0);
        }
    }
    __syncthreads();
  }
  // epilogue: LDS bounce through Cs (aliased over dead staging bufs), two 64-col halves
  float am1 = g_scal[0], am2 = g_scal[1];
  float* __restrict__ outs = out + (size_t)s*NN2;
  float (*Cs)[68] = (float(*)[68])SM;
  for (int h = 0; h < 2; h++){
    if (((wv & 3) >> 1) == h){
      #pragma unroll
      for (int i = 0; i < 4; i++)
        #pragma unroll
        for (int j = 0; j < 2; j++)
          #pragma unroll
          for (int r = 0; r < 4; r++)
            Cs[rW + i*16 + q*4 + r][(wv & 1)*32 + j*16 + m] = acc[i][j][r];
    }
    __syncthreads();
    #pragma unroll
    for (int it = 0; it < 2; it++){
      int row = it*64 + (tid >> 3);
      int c8  = (tid & 7)*8;
      float4 va = *(const float4*)&Cs[row][c8];
      float4 vb = *(const float4*)&Cs[row][c8 + 4];
      float v[8] = {va.x,va.y,va.z,va.w,vb.x,vb.y,vb.z,vb.w};
      int grow = rowBase + row;
      int col  = colBase + h*64 + c8;
      const float* ip = init + (size_t)grow*NVARS + col;
      float4 i0 = *(const float4*)ip;
      float4 i1 = *(const float4*)(ip + 4);
      float iv[8] = {i0.x,i0.y,i0.z,i0.w,i1.x,i1.y,i1.z,i1.w};
      float o[8];
      #pragma unroll
      for (int j = 0; j < 8; j++){
        float val = am1*iv[j] + am2*v[j];
        if (grow == col + j) val = -__builtin_inff();
        o[j] = val;
        atomicAdd(&hloc[fkey(val) >> 21], 1u);
      }
      float* op = outs + (size_t)grow*NVARS + col;
      *(float4*)op       = make_float4(o[0], o[1], o[2], o[3]);
      *(float4*)(op + 4) = make_float4(o[4], o[5], o[6], o[7]);
    }
    __syncthreads();
  }
  for (int i = tid; i < 2048; i += 512){
    unsigned c = hloc[i];
    if (c) atomicAdd(&g_hist[s][i], c);
  }
}

// ---------------- shared select helpers (256-thread, used by k_collect) ----
__device__ void desc_select(unsigned* h, unsigned* sc, int nb, unsigned rank,
                            unsigned* od, unsigned* orem, unsigned* ocnt){
  int tid = threadIdx.x;
  int per = nb >> 8;
  unsigned loc[8];
  unsigned own = 0;
  int base = tid*per;
  for (int j = 0; j < per; j++){ loc[j] = h[base+j]; own += loc[j]; }
  sc[tid] = own;
  __syncthreads();
  for (int off = 1; off < 256; off <<= 1){
    unsigned v = (tid + off < 256) ? sc[tid+off] : 0u;
    __syncthreads();
    sc[tid] += v;
    __syncthreads();
  }
  unsigned acc = sc[tid] - own;  // strictly-higher threads
  for (int j = per-1; j >= 0; j--){
    unsigned c = loc[j];
    if (c && rank > acc && rank <= acc + c){ *od = (unsigned)(base+j); *orem = rank - acc; *ocnt = c; }
    acc += c;
  }
  __syncthreads();
}

// ---------------- wide select helpers (1024-thread, used by k_final) -------
__device__ void desc_select_w(unsigned* h, unsigned* sc, int nb, unsigned rank,
                              unsigned* od, unsigned* orem, unsigned* ocnt){
  int tid = threadIdx.x;
  int per = nb >> 10;            // 2048 -> 2, 1024 -> 1
  unsigned loc[2] = {0u, 0u};
  unsigned own = 0;
  int base = tid*per;
  for (int j = 0; j < per; j++){ loc[j] = h[base+j]; own += loc[j]; }
  sc[tid] = own;
  __syncthreads();
  for (int off = 1; off < 1024; off <<= 1){
    unsigned v = (tid + off < 1024) ? sc[tid+off] : 0u;
    __syncthreads();
    sc[tid] += v;
    __syncthreads();
  }
  unsigned acc = sc[tid] - own;  // strictly-higher threads
  for (int j = per-1; j >= 0; j--){
    unsigned c = loc[j];
    if (c && rank > acc && rank <= acc + c){ *od = (unsigned)(base+j); *orem = rank - acc; *ocnt = c; }
    acc += c;
  }
  __syncthreads();
}
__device__ void asc_select_w(unsigned* h, unsigned* sc, int nb, unsigned rank,
                             unsigned* od, unsigned* orem){
  int tid = threadIdx.x;
  int per = nb >> 10;
  unsigned loc[2] = {0u, 0u};
  unsigned own = 0;
  int base = tid*per;
  for (int j = 0; j < per; j++){ loc[j] = h[base+j]; own += loc[j]; }
  sc[tid] = own;
  __syncthreads();
  for (int off = 1; off < 1024; off <<= 1){
    unsigned v = (tid >= off) ? sc[tid-off] : 0u;
    __syncthreads();
    sc[tid] += v;
    __syncthreads();
  }
  unsigned below = sc[tid] - own;
  for (int j = 0; j < per; j++){
    unsigned c = loc[j];
    if (c && rank > below && rank <= below + c){ *od = (unsigned)(base+j); *orem = rank - below; }
    below += c;
  }
  __syncthreads();
}

// ---------------- compact candidate (idx, fkey) in selected bin ------------
// Each block redundantly recomputes the pass-1 bin selection from g_hist
// (8 KB L2-hit + scan, ~1 us, fully parallel) -- removes the separate
// k_select1 launch + pipeline drain. Block 0 publishes prefix/krem.
__global__ __launch_bounds__(256) void k_collect(const float* __restrict__ out){
  int s = blockIdx.z;
  if (!g_state[s][0]) return;
  int tid = threadIdx.x;
  __shared__ unsigned h[2048];
  __shared__ unsigned sc[256];
  __shared__ unsigned sd, srem, scnt;
  for (int i = tid; i < 2048; i += 256) h[i] = g_hist[s][i];
  if (tid == 0){ sd = 0; srem = 1; scnt = 1; }
  __syncthreads();
  desc_select(h, sc, 2048, K_SEL, &sd, &srem, &scnt);
  unsigned pb = sd;
  if (blockIdx.x == 0 && tid == 0){ g_state[s][2] = sd << 21; g_state[s][3] = srem; }
  const float4* p = (const float4*)(out + (size_t)s*NN2);
  int stride = gridDim.x*256;
  for (int i = blockIdx.x*256 + tid; i < NN2/4; i += stride){
    float4 v = p[i];
    float xs[4] = {v.x, v.y, v.z, v.w};
    #pragma unroll
    for (int j = 0; j < 4; j++){
      unsigned u = fkey(xs[j]);
      if ((u >> 21) == pb){
        unsigned pos = atomicAdd(&g_state[s][8], 1u);
        if (pos < CAP){ g_cand[s][pos] = (unsigned)(i*4 + j); g_candk[s][pos] = u; }
      }
    }
  }
}

// ---------------- exact threshold + index tie-break among candidates --------
// 1024 threads/slot: streams cached keys (g_candk) 4x faster than the old
// 256-thread version; selection semantics byte-identical (wide scans).
__global__ __launch_bounds__(1024) void k_final(const float* __restrict__ out){
  int s = blockIdx.x;
  if (!g_state[s][0]) return;
  int tid = threadIdx.x;
  unsigned mcnt = g_state[s][8]; if (mcnt > CAP) mcnt = CAP;
  unsigned krem = g_state[s][3];
  unsigned prefix = g_state[s][2];
  (void)out;
  __shared__ unsigned h[2048];
  __shared__ unsigned sc[1024];
  __shared__ unsigned sd, srem, scnt;
  // phase 1: fkey bits 20..10
  for (int i = tid; i < 2048; i += 1024) h[i] = 0u;
  if (tid == 0){ sd = 0; srem = 1; scnt = 1; }
  __syncthreads();
  for (unsigned i = tid; i < mcnt; i += 1024){
    unsigned u = g_candk[s][i];
    atomicAdd(&h[(u >> 10) & 0x7FFu], 1u);
  }
  __syncthreads();
  desc_select_w(h, sc, 2048, krem, &sd, &srem, &scnt);
  unsigned d1 = sd, krem2 = srem;
  __syncthreads();
  // phase 2: fkey bits 9..0
  for (int i = tid; i < 2048; i += 1024) h[i] = 0u;
  __syncthreads();
  for (unsigned i = tid; i < mcnt; i += 1024){
    unsigned u = g_candk[s][i];
    if (((u >> 10) & 0x7FFu) == d1) atomicAdd(&h[u & 0x3FFu], 1u);
  }
  __syncthreads();
  desc_select_w(h, sc, 1024, krem2, &sd, &srem, &scnt);
  unsigned d0 = sd, nek = srem, cnteq = scnt;
  __syncthreads();
  unsigned tu = prefix | (d1 << 10) | d0;
  unsigned cutoff = 0x7FFFFFFFu;
  if (nek < cnteq){
    // phase 3: nek-th smallest index, high 11 bits
    for (int i = tid; i < 2048; i += 1024) h[i] = 0u;
    __syncthreads();
    for (unsigned i = tid; i < mcnt; i += 1024){
      if (g_candk[s][i] == tu) atomicAdd(&h[g_cand[s][i] >> 11], 1u);
    }
    __syncthreads();
    asc_select_w(h, sc, 2048, nek, &sd, &srem);
    unsigned dh = sd, j2 = srem;
    __syncthreads();
    // phase 4: low 11 bits
    for (int i = tid; i < 2048; i += 1024) h[i] = 0u;
    __syncthreads();
    for (unsigned i = tid; i < mcnt; i += 1024){
      unsigned idx = g_cand[s][i];
      if (g_candk[s][i] == tu && (idx >> 11) == dh) atomicAdd(&h[idx & 0x7FFu], 1u);
    }
    __syncthreads();
    asc_select_w(h, sc, 2048, j2, &sd, &srem);
    cutoff = (dh << 11) | sd;
    __syncthreads();
  }
  if (tid == 0){ g_state[s][4] = tu; g_state[s][7] = cutoff; }
}

// ---------------- mask + tanh/relu + eye + normalize + multicast to dups ----
__global__ __launch_bounds__(256) void k_masknorm(float* __restrict__ out){
  int s = blockIdx.y;
  if (!g_state[s][0]) return;
  int r = blockIdx.x;
  int tid = threadIdx.x;
  unsigned tu = g_state[s][4];
  unsigned cutoff = g_state[s][7];
  const float4* rowp = (const float4*)(out + (size_t)s*NN2 + (size_t)r*NVARS);
  unsigned baseIdx = (unsigned)(r*NVARS);
  float4 res[2];
  double lsum = 0.0;
  #pragma unroll
  for (int t = 0; t < 2; t++){
    int c4 = tid + t*256;
    float4 a4 = rowp[c4];
    float av[4] = {a4.x, a4.y, a4.z, a4.w};
    float rv[4];
    #pragma unroll
    for (int j = 0; j < 4; j++){
      int c = c4*4 + j;
      float vv;
      if (c == r) vv = 1.0f;
      else {
        unsigned u = fkey(av[j]);
        bool keep = (u > tu) || (u == tu && (baseIdx + (unsigned)c) <= cutoff);
        vv = keep ? fmaxf(tanhf(av[j]), 0.0f) : 0.0f;
      }
      rv[j] = vv;
      lsum += (double)vv;
    }
    res[t].x = rv[0]; res[t].y = rv[1]; res[t].z = rv[2]; res[t].w = rv[3];
  }
  __shared__ double red[256];
  red[tid] = lsum;
  __syncthreads();
  for (int off = 128; off > 0; off >>= 1){
    if (tid < off) red[tid] += red[tid+off];
    __syncthreads();
  }
  float inv = 1.0f / (float)red[0];
  #pragma unroll
  for (int t = 0; t < 2; t++){
    res[t].x *= inv; res[t].y *= inv; res[t].z *= inv; res[t].w *= inv;
  }
  for (int s2 = 0; s2 < NSLOT; s2++){
    if (g_state[s2][1] == (unsigned)s){
      float4* dst = (float4*)(out + (size_t)s2*NN2 + (size_t)r*NVARS);
      dst[tid]       = res[0];
      dst[tid + 256] = res[1];
    }
  }
}

// ---------------- host launcher ----------------
extern "C" void kernel_launch(void* const* d_in, const int* in_sizes, int n_in,
                              void* d_out, int out_size, void* d_ws, size_t ws_size,
                              hipStream_t stream){
  (void)in_sizes; (void)n_in; (void)d_ws; (void)ws_size; (void)out_size;
  const float* init = (const float*)d_in[0];
  const float* emb1 = (const float*)d_in[1];
  const float* emb2 = (const float*)d_in[2];
  const float* w1   = (const float*)d_in[3];
  const float* b1   = (const float*)d_in[4];
  const float* w2   = (const float*)d_in[5];
  const float* b2   = (const float*)d_in[6];
  const int* tind   = (const int*)d_in[7];
  const int* epoch  = (const int*)d_in[8];
  float* out = (float*)d_out;

  k_prep<<<1, 256, 0, stream>>>(tind, epoch);
  k_split<<<dim3(288, 1, 16), 256, 0, stream>>>(emb1, emb2, w1, w2, tind);
  k_gemm_nv<<<dim3(2, 16, 16), 256, 0, stream>>>(b1, b2, tind);
  k_gemm_s<<<dim3(16, 16, 8), 512, 0, stream>>>(init, out);
  k_collect<<<dim3(256, 1, 8), 256, 0, stream>>>(out);
  k_final<<<8, 1024, 0, stream>>>(out);
  k_masknorm<<<dim3(2048, 8), 256, 0, stream>>>(out);
}